// Round 5
// baseline (156.499 us; speedup 1.0000x reference)
//
#include <hip/hip_runtime.h>

// Round 5: (1) XCD-chunked block swizzle on all tiled kernels (T1),
// (2) single pre-cast kernel: q/k/v inputs + Wi + Wo -> bf16 so both GEMM
// operands use global_load_lds (no cvt in hot loops), (3) attention fused
// into ONE direct masked kernel: out = 0.125 * tril(Q K^T) V per (bh,qtile),
// replacing chunkkv+prefix+chunkout (linear attention needs no prefix state).

#define E_DIM 1024

typedef short bf16x8 __attribute__((ext_vector_type(8)));
typedef float f32x4  __attribute__((ext_vector_type(4)));

__device__ inline unsigned short f2bf(float f) {
    unsigned u = __builtin_bit_cast(unsigned, f);
    u = (u + 0x7FFFu + ((u >> 16) & 1u)) >> 16;   // RNE; inputs finite
    return (unsigned short)u;
}

__device__ inline void gload_lds16(const void* g, void* l) {
    __builtin_amdgcn_global_load_lds(
        (const __attribute__((address_space(1))) unsigned int*)g,
        (__attribute__((address_space(3))) unsigned int*)l, 16, 0, 0);
}

// ---------------------------------------------------------------------------
// Kernel 0: cast everything to bf16, contiguous dst:
//   [xq 2M][xk 2M][xv 2M][Wi 3M][Wo 1M] elements (10M total, 1.25M float8).
// ---------------------------------------------------------------------------
__global__ __launch_bounds__(256) void k_cast(
    const float* __restrict__ q_in, const float* __restrict__ k_in,
    const float* __restrict__ v_in, const float* __restrict__ w_in,
    const float* __restrict__ w_out, unsigned short* __restrict__ dst)
{
    #pragma unroll
    for (int l = 0; l < 4; ++l) {
        int id8 = blockIdx.x * 256 + threadIdx.x + l * 327680;
        const float* src;
        if (id8 < 262144)        src = q_in  + (size_t)id8 * 8;
        else if (id8 < 524288)   src = k_in  + (size_t)(id8 - 262144) * 8;
        else if (id8 < 786432)   src = v_in  + (size_t)(id8 - 524288) * 8;
        else if (id8 < 1179648)  src = w_in  + (size_t)(id8 - 786432) * 8;
        else                     src = w_out + (size_t)(id8 - 1179648) * 8;
        float4 f0 = *reinterpret_cast<const float4*>(src);
        float4 f1 = *reinterpret_cast<const float4*>(src + 4);
        ushort4 o0, o1;
        o0.x = f2bf(f0.x); o0.y = f2bf(f0.y); o0.z = f2bf(f0.z); o0.w = f2bf(f0.w);
        o1.x = f2bf(f1.x); o1.y = f2bf(f1.y); o1.z = f2bf(f1.z); o1.w = f2bf(f1.w);
        *reinterpret_cast<ushort4*>(dst + (size_t)id8 * 8)     = o0;
        *reinterpret_cast<ushort4*>(dst + (size_t)id8 * 8 + 4) = o1;
    }
}

// ---------------------------------------------------------------------------
// Kernel 1: in-projection GEMM, 64x128 tile, BK=64, both operands bf16 via
// global_load_lds. Grid 768 linear, XCD-chunked swizzle (cpx=96): the 8
// n-tiles of one (m,z) row-tile land on one XCD -> A fetched once, W hot in L2.
// Epilogue: z=0 Q natural [b][t][e]; z=1 K natural; z=2 V transposed [b][e][t].
// ---------------------------------------------------------------------------
__global__ __launch_bounds__(256) void k_gin(
    const unsigned short* __restrict__ xbf, const unsigned short* __restrict__ Wibf,
    const float* __restrict__ b_in,
    unsigned short* __restrict__ qslab, unsigned short* __restrict__ kslab,
    unsigned short* __restrict__ vtb)
{
    const int i = blockIdx.x;
    const int tile = (i & 7) * 96 + (i >> 3);     // 768 = 8 XCD * 96
    const int x = tile & 7, y = (tile >> 3) & 31, z = tile >> 8;

    const unsigned short* X = xbf + (size_t)z * 2097152;
    const unsigned short* W = Wibf + (size_t)z * 1048576;
    const float* bz = b_in + z * E_DIM;

    const int nBase = x * 128;
    const int mBase = y * 64;                     // b-major row space
    const int b = mBase >> 10, tBase = mBase & 1023;

    __shared__ short As[64 * 64];
    __shared__ short Bs[128 * 64];

    const int tid = threadIdx.x;
    const int lane = tid & 63, wave = tid >> 6;
    const int wr = wave >> 1, wc = wave & 1;
    const int l15 = lane & 15, l4 = lane >> 4;

    f32x4 acc[2][4] = {};

    for (int k0 = 0; k0 < E_DIM; k0 += 64) {
        #pragma unroll
        for (int l = 0; l < 4; ++l) {             // B: 128x64 bf16
            int off = l * 4096 + tid * 16;
            int row = off >> 7, kb = off & 127;
            gload_lds16((const char*)W + ((size_t)(nBase + row) * E_DIM + k0) * 2 + kb,
                        (char*)Bs + off);
        }
        #pragma unroll
        for (int l = 0; l < 2; ++l) {             // A: 64x64 bf16
            int off = l * 4096 + tid * 16;
            int row = off >> 7, kb = off & 127;
            gload_lds16((const char*)X +
                            ((size_t)((tBase + row) * 2 + b) * E_DIM + k0) * 2 + kb,
                        (char*)As + off);
        }
        __syncthreads();

        #pragma unroll
        for (int kk = 0; kk < 64; kk += 32) {
            bf16x8 af[2], bfr[4];
            #pragma unroll
            for (int ii = 0; ii < 2; ++ii)
                af[ii] = *reinterpret_cast<const bf16x8*>(
                            &As[(wr * 32 + ii * 16 + l15) * 64 + kk + l4 * 8]);
            #pragma unroll
            for (int j = 0; j < 4; ++j)
                bfr[j] = *reinterpret_cast<const bf16x8*>(
                            &Bs[(wc * 64 + j * 16 + l15) * 64 + kk + l4 * 8]);
            #pragma unroll
            for (int ii = 0; ii < 2; ++ii)
                #pragma unroll
                for (int j = 0; j < 4; ++j)
                    acc[ii][j] = __builtin_amdgcn_mfma_f32_16x16x32_bf16(
                        af[ii], bfr[j], acc[ii][j], 0, 0, 0);
        }
        __syncthreads();
    }

    #pragma unroll
    for (int ii = 0; ii < 2; ++ii) {
        int t0 = tBase + wr * 32 + ii * 16 + l4 * 4;
        #pragma unroll
        for (int j = 0; j < 4; ++j) {
            int col = nBase + wc * 64 + j * 16 + l15;
            float bv = bz[col];
            unsigned short v4[4];
            #pragma unroll
            for (int q = 0; q < 4; ++q) v4[q] = f2bf(acc[ii][j][q] + bv);
            if (z == 0) {
                #pragma unroll
                for (int q = 0; q < 4; ++q)
                    qslab[(size_t)b * 1048576 + (size_t)(t0 + q) * E_DIM + col] = v4[q];
            } else if (z == 1) {
                #pragma unroll
                for (int q = 0; q < 4; ++q)
                    kslab[(size_t)b * 1048576 + (size_t)(t0 + q) * E_DIM + col] = v4[q];
            } else {
                ushort4 w = {v4[0], v4[1], v4[2], v4[3]};
                *reinterpret_cast<ushort4*>(
                    &vtb[((size_t)b * 1024 + col) * 1024 + t0]) = w;
            }
        }
    }
}

// ---------------------------------------------------------------------------
// Kernel 2: direct masked linear attention. Per block (bh, qtile of 64 rows):
//   O = 0.125 * sum_{kv tiles c<=qt} [mask_if_diag(Q Kc^T)] Vc
// Grid 512 linear, XCD-chunked (cpx=64 -> 4 bh per XCD, K/V hot in L2).
// Within-XCD qt ordering pairs complementary workloads (u vs u+32).
// ---------------------------------------------------------------------------
__global__ __launch_bounds__(256) void k_attn(
    const unsigned short* __restrict__ qslab, const unsigned short* __restrict__ kslab,
    const unsigned short* __restrict__ vtb, unsigned short* __restrict__ attnbf)
{
    const int i = blockIdx.x;
    const int xcd = i & 7, u = i >> 3;            // u in 0..63
    const int bh = xcd * 4 + (u >> 4);
    const int qtr = u & 15;
    const int qt = ((u >> 5) & 1) ? (15 - qtr) : qtr;   // complementary pairing
    const int b = bh >> 4, h = bh & 15;
    const int colb = h * 64, t0q = qt * 64;

    __shared__ short Qs[64 * 64];
    __shared__ short Ks[64 * 64];
    __shared__ short Vts[64 * 64];
    __shared__ short Ss[64 * 72];

    const int tid = threadIdx.x;
    const int lane = tid & 63, wave = tid >> 6;
    const int wr = wave >> 1, wc = wave & 1;
    const int l15 = lane & 15, l4 = lane >> 4;

    #pragma unroll
    for (int l = 0; l < 2; ++l) {                 // stage Q once
        int off = l * 4096 + tid * 16;
        int row = off >> 7, kb = off & 127;
        gload_lds16((const char*)qslab +
                        ((size_t)b * 1048576 + (size_t)(t0q + row) * E_DIM + colb) * 2 + kb,
                    (char*)Qs + off);
    }

    f32x4 oacc[2][2] = {};

    for (int c = 0; c <= qt; ++c) {
        const int t0k = c * 64;
        #pragma unroll
        for (int l = 0; l < 2; ++l) {
            int off = l * 4096 + tid * 16;
            int row = off >> 7, kb = off & 127;
            gload_lds16((const char*)kslab +
                            ((size_t)b * 1048576 + (size_t)(t0k + row) * E_DIM + colb) * 2 + kb,
                        (char*)Ks + off);
            gload_lds16((const char*)vtb +
                            (((size_t)b * 1024 + colb + row) * 1024 + t0k) * 2 + kb,
                        (char*)Vts + off);
        }
        __syncthreads();

        // S = Q Kc^T  (contract over d)
        f32x4 sacc[2][2] = {};
        #pragma unroll
        for (int kk = 0; kk < 64; kk += 32) {
            bf16x8 af[2], bfr[2];
            #pragma unroll
            for (int ii = 0; ii < 2; ++ii)
                af[ii] = *reinterpret_cast<const bf16x8*>(
                            &Qs[(wr * 32 + ii * 16 + l15) * 64 + kk + l4 * 8]);
            #pragma unroll
            for (int j = 0; j < 2; ++j)
                bfr[j] = *reinterpret_cast<const bf16x8*>(
                            &Ks[(wc * 32 + j * 16 + l15) * 64 + kk + l4 * 8]);
            #pragma unroll
            for (int ii = 0; ii < 2; ++ii)
                #pragma unroll
                for (int j = 0; j < 2; ++j)
                    sacc[ii][j] = __builtin_amdgcn_mfma_f32_16x16x32_bf16(
                        af[ii], bfr[j], sacc[ii][j], 0, 0, 0);
        }
        // mask (only diagonal tile) + cvt -> Ss (padded, stride 72)
        const bool diag = (c == qt);
        #pragma unroll
        for (int ii = 0; ii < 2; ++ii) {
            #pragma unroll
            for (int j = 0; j < 2; ++j) {
                int kr = wc * 32 + j * 16 + l15;
                #pragma unroll
                for (int q = 0; q < 4; ++q) {
                    int qr = wr * 32 + ii * 16 + l4 * 4 + q;
                    short sv = (short)f2bf(sacc[ii][j][q]);
                    Ss[qr * 72 + kr] = (!diag || kr <= qr) ? sv : (short)0;
                }
            }
        }
        __syncthreads();

        // O += S Vc  (contract over s)
        #pragma unroll
        for (int kk = 0; kk < 64; kk += 32) {
            bf16x8 af[2], bfr[2];
            #pragma unroll
            for (int ii = 0; ii < 2; ++ii)
                af[ii] = *reinterpret_cast<const bf16x8*>(
                            &Ss[(wr * 32 + ii * 16 + l15) * 72 + kk + l4 * 8]);
            #pragma unroll
            for (int j = 0; j < 2; ++j)
                bfr[j] = *reinterpret_cast<const bf16x8*>(
                            &Vts[(wc * 32 + j * 16 + l15) * 64 + kk + l4 * 8]);
            #pragma unroll
            for (int ii = 0; ii < 2; ++ii)
                #pragma unroll
                for (int j = 0; j < 2; ++j)
                    oacc[ii][j] = __builtin_amdgcn_mfma_f32_16x16x32_bf16(
                        af[ii], bfr[j], oacc[ii][j], 0, 0, 0);
        }
        __syncthreads();                          // protect Ks/Vts/Ss overwrite
    }

    #pragma unroll
    for (int ii = 0; ii < 2; ++ii) {
        #pragma unroll
        for (int j = 0; j < 2; ++j) {
            int dv = wc * 32 + j * 16 + l15;
            #pragma unroll
            for (int q = 0; q < 4; ++q) {
                int qr = wr * 32 + ii * 16 + l4 * 4 + q;
                attnbf[(size_t)b * 1048576 + (size_t)(t0q + qr) * E_DIM + colb + dv] =
                    f2bf(oacc[ii][j][q] * 0.125f);
            }
        }
    }
}

// ---------------------------------------------------------------------------
// Kernel 3: out-projection GEMM, 64x128 tile, both operands bf16 gload.
// Grid 256 linear, XCD-chunked (cpx=32). fp32 output rows r = t*2+b.
// ---------------------------------------------------------------------------
__global__ __launch_bounds__(256) void k_gout(
    const unsigned short* __restrict__ attnbf, const unsigned short* __restrict__ Wobf,
    const float* __restrict__ bias, float* __restrict__ out)
{
    const int i = blockIdx.x;
    const int tile = (i & 7) * 32 + (i >> 3);     // 256 = 8 * 32
    const int x = tile & 7, y = tile >> 3;
    const int nBase = x * 128;
    const int mBase = y * 64;                     // r-space (t*2+b)

    __shared__ short As[64 * 64];
    __shared__ short Bs[128 * 64];

    const int tid = threadIdx.x;
    const int lane = tid & 63, wave = tid >> 6;
    const int wr = wave >> 1, wc = wave & 1;
    const int l15 = lane & 15, l4 = lane >> 4;

    f32x4 acc[2][4] = {};

    for (int k0 = 0; k0 < E_DIM; k0 += 64) {
        #pragma unroll
        for (int l = 0; l < 4; ++l) {
            int off = l * 4096 + tid * 16;
            int row = off >> 7, kb = off & 127;
            gload_lds16((const char*)Wobf + ((size_t)(nBase + row) * E_DIM + k0) * 2 + kb,
                        (char*)Bs + off);
        }
        #pragma unroll
        for (int l = 0; l < 2; ++l) {
            int off = l * 4096 + tid * 16;
            int row = off >> 7, kb = off & 127;
            int r = mBase + row, t = r >> 1, bb = r & 1;
            gload_lds16((const char*)attnbf +
                            ((size_t)bb * 1048576 + (size_t)t * E_DIM + k0) * 2 + kb,
                        (char*)As + off);
        }
        __syncthreads();

        #pragma unroll
        for (int kk = 0; kk < 64; kk += 32) {
            bf16x8 af[2], bfr[4];
            #pragma unroll
            for (int ii = 0; ii < 2; ++ii)
                af[ii] = *reinterpret_cast<const bf16x8*>(
                            &As[(wr * 32 + ii * 16 + l15) * 64 + kk + l4 * 8]);
            #pragma unroll
            for (int j = 0; j < 4; ++j)
                bfr[j] = *reinterpret_cast<const bf16x8*>(
                            &Bs[(wc * 64 + j * 16 + l15) * 64 + kk + l4 * 8]);
            #pragma unroll
            for (int ii = 0; ii < 2; ++ii)
                #pragma unroll
                for (int j = 0; j < 4; ++j)
                    acc[ii][j] = __builtin_amdgcn_mfma_f32_16x16x32_bf16(
                        af[ii], bfr[j], acc[ii][j], 0, 0, 0);
        }
        __syncthreads();
    }

    #pragma unroll
    for (int ii = 0; ii < 2; ++ii) {
        int r0 = mBase + wr * 32 + ii * 16 + l4 * 4;
        #pragma unroll
        for (int j = 0; j < 4; ++j) {
            int col = nBase + wc * 64 + j * 16 + l15;
            float bv = bias[col];
            #pragma unroll
            for (int q = 0; q < 4; ++q)
                out[(size_t)(r0 + q) * E_DIM + col] = acc[ii][j][q] + bv;
        }
    }
}

// ---------------------------------------------------------------------------
extern "C" void kernel_launch(void* const* d_in, const int* in_sizes, int n_in,
                              void* d_out, int out_size, void* d_ws, size_t ws_size,
                              hipStream_t stream)
{
    const float* q_in  = (const float*)d_in[0];
    const float* k_in  = (const float*)d_in[1];
    const float* v_in  = (const float*)d_in[2];
    const float* w_in  = (const float*)d_in[3];
    const float* b_in  = (const float*)d_in[4];
    const float* w_out = (const float*)d_in[5];
    const float* b_out = (const float*)d_in[6];

    // ws layout (36 MiB):
    //   [ 0, 4M)  xq bf16      [ 4M, 8M)  xk bf16     [ 8M,12M)  xv bf16
    //   [12M,18M) Wi bf16      [18M,20M)  Wo bf16
    //   [20M,24M) qslab bf16 [b][t][e]    [24M,28M) kslab bf16 [b][t][e]
    //   [28M,32M) vtb bf16 [b][e][t]      [32M,36M) attnbf bf16 [b][t][e]
    char* w = (char*)d_ws;
    unsigned short* xbf    = (unsigned short*)w;
    unsigned short* Wibf   = (unsigned short*)(w + 12582912);
    unsigned short* Wobf   = (unsigned short*)(w + 18874368);
    unsigned short* qslab  = (unsigned short*)(w + 20971520);
    unsigned short* kslab  = (unsigned short*)(w + 25165824);
    unsigned short* vtb    = (unsigned short*)(w + 29360128);
    unsigned short* attnbf = (unsigned short*)(w + 33554432);
    float* outp = (float*)d_out;

    k_cast<<<1280, 256, 0, stream>>>(q_in, k_in, v_in, w_in, w_out, xbf);
    k_gin<<<768, 256, 0, stream>>>(xbf, Wibf, b_in, qslab, kslab, vtb);
    k_attn<<<512, 256, 0, stream>>>(qslab, kslab, vtb, attnbf);
    k_gout<<<256, 256, 0, stream>>>(attnbf, Wobf, b_out, outp);
}

// Round 6
// 153.953 us; speedup vs baseline: 1.0165x; 1.0165x over previous
//
#include <hip/hip_runtime.h>

// Round 6: T3-minimal software pipelining (double-buffered LDS, prefetch
// issued before compute, ONE barrier per K-step) on k_gin / k_attn / k_gout;
// k_gout retiled 64x64 so grid=512 (2 blocks/CU). XCD-chunked swizzle kept.

#define E_DIM 1024

typedef short bf16x8 __attribute__((ext_vector_type(8)));
typedef float f32x4  __attribute__((ext_vector_type(4)));

__device__ inline unsigned short f2bf(float f) {
    unsigned u = __builtin_bit_cast(unsigned, f);
    u = (u + 0x7FFFu + ((u >> 16) & 1u)) >> 16;   // RNE; inputs finite
    return (unsigned short)u;
}

__device__ inline void gload_lds16(const void* g, void* l) {
    __builtin_amdgcn_global_load_lds(
        (const __attribute__((address_space(1))) unsigned int*)g,
        (__attribute__((address_space(3))) unsigned int*)l, 16, 0, 0);
}

// ---------------------------------------------------------------------------
// Kernel 0: cast everything to bf16, contiguous dst:
//   [xq 2M][xk 2M][xv 2M][Wi 3M][Wo 1M] elements (10M total, 1.25M float8).
// ---------------------------------------------------------------------------
__global__ __launch_bounds__(256) void k_cast(
    const float* __restrict__ q_in, const float* __restrict__ k_in,
    const float* __restrict__ v_in, const float* __restrict__ w_in,
    const float* __restrict__ w_out, unsigned short* __restrict__ dst)
{
    #pragma unroll
    for (int l = 0; l < 4; ++l) {
        int id8 = blockIdx.x * 256 + threadIdx.x + l * 327680;
        const float* src;
        if (id8 < 262144)        src = q_in  + (size_t)id8 * 8;
        else if (id8 < 524288)   src = k_in  + (size_t)(id8 - 262144) * 8;
        else if (id8 < 786432)   src = v_in  + (size_t)(id8 - 524288) * 8;
        else if (id8 < 1179648)  src = w_in  + (size_t)(id8 - 786432) * 8;
        else                     src = w_out + (size_t)(id8 - 1179648) * 8;
        float4 f0 = *reinterpret_cast<const float4*>(src);
        float4 f1 = *reinterpret_cast<const float4*>(src + 4);
        ushort4 o0, o1;
        o0.x = f2bf(f0.x); o0.y = f2bf(f0.y); o0.z = f2bf(f0.z); o0.w = f2bf(f0.w);
        o1.x = f2bf(f1.x); o1.y = f2bf(f1.y); o1.z = f2bf(f1.z); o1.w = f2bf(f1.w);
        *reinterpret_cast<ushort4*>(dst + (size_t)id8 * 8)     = o0;
        *reinterpret_cast<ushort4*>(dst + (size_t)id8 * 8 + 4) = o1;
    }
}

// ---------------------------------------------------------------------------
// Kernel 1: in-projection GEMM, 64x128 tile, BK=64, double-buffered LDS,
// prefetch-before-compute, one barrier per K-step. Grid 768, XCD-chunked.
// Epilogue: z=0 Q natural [b][t][e]; z=1 K natural; z=2 V transposed [b][e][t].
// ---------------------------------------------------------------------------
__global__ __launch_bounds__(256) void k_gin(
    const unsigned short* __restrict__ xbf, const unsigned short* __restrict__ Wibf,
    const float* __restrict__ b_in,
    unsigned short* __restrict__ qslab, unsigned short* __restrict__ kslab,
    unsigned short* __restrict__ vtb)
{
    const int i = blockIdx.x;
    const int tile = (i & 7) * 96 + (i >> 3);     // 768 = 8 XCD * 96
    const int x = tile & 7, y = (tile >> 3) & 31, z = tile >> 8;

    const unsigned short* X = xbf + (size_t)z * 2097152;
    const unsigned short* W = Wibf + (size_t)z * 1048576;
    const float* bz = b_in + z * E_DIM;

    const int nBase = x * 128;
    const int mBase = y * 64;                     // b-major row space
    const int b = mBase >> 10, tBase = mBase & 1023;

    __shared__ short As[2][64 * 64];
    __shared__ short Bs[2][128 * 64];

    const int tid = threadIdx.x;
    const int lane = tid & 63, wave = tid >> 6;
    const int wr = wave >> 1, wc = wave & 1;
    const int l15 = lane & 15, l4 = lane >> 4;

    auto stageAB = [&](int bufI, int k0) {
        #pragma unroll
        for (int l = 0; l < 4; ++l) {             // B: 128x64 bf16 = 16KB
            int off = l * 4096 + tid * 16;
            int row = off >> 7, kb = off & 127;
            gload_lds16((const char*)W + ((size_t)(nBase + row) * E_DIM + k0) * 2 + kb,
                        (char*)&Bs[bufI][0] + off);
        }
        #pragma unroll
        for (int l = 0; l < 2; ++l) {             // A: 64x64 bf16 = 8KB
            int off = l * 4096 + tid * 16;
            int row = off >> 7, kb = off & 127;
            gload_lds16((const char*)X +
                            ((size_t)((tBase + row) * 2 + b) * E_DIM + k0) * 2 + kb,
                        (char*)&As[bufI][0] + off);
        }
    };

    f32x4 acc[2][4] = {};

    stageAB(0, 0);
    __syncthreads();
    int cur = 0;
    for (int it = 0; it < 16; ++it) {
        if (it < 15) stageAB(cur ^ 1, (it + 1) * 64);   // prefetch next tile
        #pragma unroll
        for (int kk = 0; kk < 64; kk += 32) {
            bf16x8 af[2], bfr[4];
            #pragma unroll
            for (int ii = 0; ii < 2; ++ii)
                af[ii] = *reinterpret_cast<const bf16x8*>(
                            &As[cur][(wr * 32 + ii * 16 + l15) * 64 + kk + l4 * 8]);
            #pragma unroll
            for (int j = 0; j < 4; ++j)
                bfr[j] = *reinterpret_cast<const bf16x8*>(
                            &Bs[cur][(wc * 64 + j * 16 + l15) * 64 + kk + l4 * 8]);
            #pragma unroll
            for (int ii = 0; ii < 2; ++ii)
                #pragma unroll
                for (int j = 0; j < 4; ++j)
                    acc[ii][j] = __builtin_amdgcn_mfma_f32_16x16x32_bf16(
                        af[ii], bfr[j], acc[ii][j], 0, 0, 0);
        }
        __syncthreads();            // implicit vmcnt(0): prefetch landed, bufs safe
        cur ^= 1;
    }

    #pragma unroll
    for (int ii = 0; ii < 2; ++ii) {
        int t0 = tBase + wr * 32 + ii * 16 + l4 * 4;
        #pragma unroll
        for (int j = 0; j < 4; ++j) {
            int col = nBase + wc * 64 + j * 16 + l15;
            float bv = bz[col];
            unsigned short v4[4];
            #pragma unroll
            for (int q = 0; q < 4; ++q) v4[q] = f2bf(acc[ii][j][q] + bv);
            if (z == 0) {
                #pragma unroll
                for (int q = 0; q < 4; ++q)
                    qslab[(size_t)b * 1048576 + (size_t)(t0 + q) * E_DIM + col] = v4[q];
            } else if (z == 1) {
                #pragma unroll
                for (int q = 0; q < 4; ++q)
                    kslab[(size_t)b * 1048576 + (size_t)(t0 + q) * E_DIM + col] = v4[q];
            } else {
                ushort4 w = {v4[0], v4[1], v4[2], v4[3]};
                *reinterpret_cast<ushort4*>(
                    &vtb[((size_t)b * 1024 + col) * 1024 + t0]) = w;
            }
        }
    }
}

// ---------------------------------------------------------------------------
// Kernel 2: direct masked linear attention, K/V double-buffered with prefetch
// under the QK^T phase. Per block (bh, qtile): O = 0.125*sum_{c<=qt} mask(QKc^T)Vc
// Grid 512, XCD-chunked (4 bh per XCD); complementary qt pairing balances load.
// ---------------------------------------------------------------------------
__global__ __launch_bounds__(256) void k_attn(
    const unsigned short* __restrict__ qslab, const unsigned short* __restrict__ kslab,
    const unsigned short* __restrict__ vtb, unsigned short* __restrict__ attnbf)
{
    const int i = blockIdx.x;
    const int xcd = i & 7, u = i >> 3;            // u in 0..63
    const int bh = xcd * 4 + (u >> 4);
    const int qtr = u & 15;
    const int qt = ((u >> 5) & 1) ? (15 - qtr) : qtr;
    const int b = bh >> 4, h = bh & 15;
    const int colb = h * 64, t0q = qt * 64;

    __shared__ short Qs[64 * 64];
    __shared__ short Ks[2][64 * 64];
    __shared__ short Vts[2][64 * 64];
    __shared__ short Ss[64 * 72];

    const int tid = threadIdx.x;
    const int lane = tid & 63, wave = tid >> 6;
    const int wr = wave >> 1, wc = wave & 1;
    const int l15 = lane & 15, l4 = lane >> 4;

    auto stageKV = [&](int bufI, int c) {
        int t0k = c * 64;
        #pragma unroll
        for (int l = 0; l < 2; ++l) {
            int off = l * 4096 + tid * 16;
            int row = off >> 7, kb = off & 127;
            gload_lds16((const char*)kslab +
                            ((size_t)b * 1048576 + (size_t)(t0k + row) * E_DIM + colb) * 2 + kb,
                        (char*)&Ks[bufI][0] + off);
            gload_lds16((const char*)vtb +
                            (((size_t)(b * 1024 + colb + row)) * 1024 + t0k) * 2 + kb,
                        (char*)&Vts[bufI][0] + off);
        }
    };

    #pragma unroll
    for (int l = 0; l < 2; ++l) {                 // stage Q once
        int off = l * 4096 + tid * 16;
        int row = off >> 7, kb = off & 127;
        gload_lds16((const char*)qslab +
                        ((size_t)b * 1048576 + (size_t)(t0q + row) * E_DIM + colb) * 2 + kb,
                    (char*)Qs + off);
    }
    stageKV(0, 0);
    __syncthreads();

    f32x4 oacc[2][2] = {};
    int cur = 0;

    for (int c = 0; c <= qt; ++c) {
        if (c < qt) stageKV(cur ^ 1, c + 1);      // prefetch next K/V tile

        // S = Q Kc^T  (contract over d)
        f32x4 sacc[2][2] = {};
        #pragma unroll
        for (int kk = 0; kk < 64; kk += 32) {
            bf16x8 af[2], bfr[2];
            #pragma unroll
            for (int ii = 0; ii < 2; ++ii)
                af[ii] = *reinterpret_cast<const bf16x8*>(
                            &Qs[(wr * 32 + ii * 16 + l15) * 64 + kk + l4 * 8]);
            #pragma unroll
            for (int j = 0; j < 2; ++j)
                bfr[j] = *reinterpret_cast<const bf16x8*>(
                            &Ks[cur][(wc * 32 + j * 16 + l15) * 64 + kk + l4 * 8]);
            #pragma unroll
            for (int ii = 0; ii < 2; ++ii)
                #pragma unroll
                for (int j = 0; j < 2; ++j)
                    sacc[ii][j] = __builtin_amdgcn_mfma_f32_16x16x32_bf16(
                        af[ii], bfr[j], sacc[ii][j], 0, 0, 0);
        }
        // mask (diagonal tile only) + cvt -> Ss (padded stride 72)
        const bool diag = (c == qt);
        #pragma unroll
        for (int ii = 0; ii < 2; ++ii) {
            #pragma unroll
            for (int j = 0; j < 2; ++j) {
                int kr = wc * 32 + j * 16 + l15;
                #pragma unroll
                for (int q = 0; q < 4; ++q) {
                    int qr = wr * 32 + ii * 16 + l4 * 4 + q;
                    short sv = (short)f2bf(sacc[ii][j][q]);
                    Ss[qr * 72 + kr] = (!diag || kr <= qr) ? sv : (short)0;
                }
            }
        }
        __syncthreads();

        // O += S Vc  (contract over s)
        #pragma unroll
        for (int kk = 0; kk < 64; kk += 32) {
            bf16x8 af[2], bfr[2];
            #pragma unroll
            for (int ii = 0; ii < 2; ++ii)
                af[ii] = *reinterpret_cast<const bf16x8*>(
                            &Ss[(wr * 32 + ii * 16 + l15) * 72 + kk + l4 * 8]);
            #pragma unroll
            for (int j = 0; j < 2; ++j)
                bfr[j] = *reinterpret_cast<const bf16x8*>(
                            &Vts[cur][(wc * 32 + j * 16 + l15) * 64 + kk + l4 * 8]);
            #pragma unroll
            for (int ii = 0; ii < 2; ++ii)
                #pragma unroll
                for (int j = 0; j < 2; ++j)
                    oacc[ii][j] = __builtin_amdgcn_mfma_f32_16x16x32_bf16(
                        af[ii], bfr[j], oacc[ii][j], 0, 0, 0);
        }
        __syncthreads();            // Ss/K/V[cur] safe to overwrite; prefetch landed
        cur ^= 1;
    }

    #pragma unroll
    for (int ii = 0; ii < 2; ++ii) {
        #pragma unroll
        for (int j = 0; j < 2; ++j) {
            int dv = wc * 32 + j * 16 + l15;
            #pragma unroll
            for (int q = 0; q < 4; ++q) {
                int qr = wr * 32 + ii * 16 + l4 * 4 + q;
                attnbf[(size_t)b * 1048576 + (size_t)(t0q + qr) * E_DIM + colb + dv] =
                    f2bf(oacc[ii][j][q] * 0.125f);
            }
        }
    }
}

// ---------------------------------------------------------------------------
// Kernel 3: out-projection GEMM, 64x64 tile (grid 512 -> 2 blocks/CU),
// double-buffered + prefetch, one barrier per K-step. XCD-chunked swizzle.
// fp32 output rows r = t*2+b.
// ---------------------------------------------------------------------------
__global__ __launch_bounds__(256) void k_gout(
    const unsigned short* __restrict__ attnbf, const unsigned short* __restrict__ Wobf,
    const float* __restrict__ bias, float* __restrict__ out)
{
    const int i = blockIdx.x;
    const int tile = (i & 7) * 64 + (i >> 3);     // 512 = 8 * 64
    const int x = tile & 15, y = tile >> 4;       // 16 n-tiles, 32 m-tiles
    const int nBase = x * 64;
    const int mBase = y * 64;                     // r-space (t*2+b)

    __shared__ short As[2][64 * 64];
    __shared__ short Bs[2][64 * 64];

    const int tid = threadIdx.x;
    const int lane = tid & 63, wave = tid >> 6;
    const int wr = wave >> 1, wc = wave & 1;
    const int l15 = lane & 15, l4 = lane >> 4;

    auto stage = [&](int bufI, int k0) {
        #pragma unroll
        for (int l = 0; l < 2; ++l) {
            int off = l * 4096 + tid * 16;
            int row = off >> 7, kb = off & 127;
            gload_lds16((const char*)Wobf + ((size_t)(nBase + row) * E_DIM + k0) * 2 + kb,
                        (char*)&Bs[bufI][0] + off);
            int r = mBase + row, t = r >> 1, bb = r & 1;
            gload_lds16((const char*)attnbf +
                            ((size_t)bb * 1048576 + (size_t)t * E_DIM + k0) * 2 + kb,
                        (char*)&As[bufI][0] + off);
        }
    };

    f32x4 acc[2][2] = {};

    stage(0, 0);
    __syncthreads();
    int cur = 0;
    for (int it = 0; it < 16; ++it) {
        if (it < 15) stage(cur ^ 1, (it + 1) * 64);
        #pragma unroll
        for (int kk = 0; kk < 64; kk += 32) {
            bf16x8 af[2], bfr[2];
            #pragma unroll
            for (int ii = 0; ii < 2; ++ii)
                af[ii] = *reinterpret_cast<const bf16x8*>(
                            &As[cur][(wr * 32 + ii * 16 + l15) * 64 + kk + l4 * 8]);
            #pragma unroll
            for (int j = 0; j < 2; ++j)
                bfr[j] = *reinterpret_cast<const bf16x8*>(
                            &Bs[cur][(wc * 32 + j * 16 + l15) * 64 + kk + l4 * 8]);
            #pragma unroll
            for (int ii = 0; ii < 2; ++ii)
                #pragma unroll
                for (int j = 0; j < 2; ++j)
                    acc[ii][j] = __builtin_amdgcn_mfma_f32_16x16x32_bf16(
                        af[ii], bfr[j], acc[ii][j], 0, 0, 0);
        }
        __syncthreads();
        cur ^= 1;
    }

    #pragma unroll
    for (int ii = 0; ii < 2; ++ii) {
        int r0 = mBase + wr * 32 + ii * 16 + l4 * 4;
        #pragma unroll
        for (int j = 0; j < 2; ++j) {
            int col = nBase + wc * 32 + j * 16 + l15;
            float bv = bias[col];
            #pragma unroll
            for (int q = 0; q < 4; ++q)
                out[(size_t)(r0 + q) * E_DIM + col] = acc[ii][j][q] + bv;
        }
    }
}

// ---------------------------------------------------------------------------
extern "C" void kernel_launch(void* const* d_in, const int* in_sizes, int n_in,
                              void* d_out, int out_size, void* d_ws, size_t ws_size,
                              hipStream_t stream)
{
    const float* q_in  = (const float*)d_in[0];
    const float* k_in  = (const float*)d_in[1];
    const float* v_in  = (const float*)d_in[2];
    const float* w_in  = (const float*)d_in[3];
    const float* b_in  = (const float*)d_in[4];
    const float* w_out = (const float*)d_in[5];
    const float* b_out = (const float*)d_in[6];

    // ws layout (36 MiB):
    //   [ 0, 4M)  xq bf16      [ 4M, 8M)  xk bf16     [ 8M,12M)  xv bf16
    //   [12M,18M) Wi bf16      [18M,20M)  Wo bf16
    //   [20M,24M) qslab bf16 [b][t][e]    [24M,28M) kslab bf16 [b][t][e]
    //   [28M,32M) vtb bf16 [b][e][t]      [32M,36M) attnbf bf16 [b][t][e]
    char* w = (char*)d_ws;
    unsigned short* xbf    = (unsigned short*)w;
    unsigned short* Wibf   = (unsigned short*)(w + 12582912);
    unsigned short* Wobf   = (unsigned short*)(w + 18874368);
    unsigned short* qslab  = (unsigned short*)(w + 20971520);
    unsigned short* kslab  = (unsigned short*)(w + 25165824);
    unsigned short* vtb    = (unsigned short*)(w + 29360128);
    unsigned short* attnbf = (unsigned short*)(w + 33554432);
    float* outp = (float*)d_out;

    k_cast<<<1280, 256, 0, stream>>>(q_in, k_in, v_in, w_in, w_out, xbf);
    k_gin<<<768, 256, 0, stream>>>(xbf, Wibf, b_in, qslab, kslab, vtb);
    k_attn<<<512, 256, 0, stream>>>(qslab, kslab, vtb, attnbf);
    k_gout<<<512, 256, 0, stream>>>(attnbf, Wobf, b_out, outp);
}